// Round 5
// baseline (141.724 us; speedup 1.0000x reference)
//
#include <hip/hip_runtime.h>

// MultiHeadSelfAttention: B=8 N=1024 E=768 H=12 D=64
// Pipeline: cvt(x) / transpose-cvt(Wqkv,Wfc)
//           -> GEMM1 (m97-structure bf16 mfma, epilogue -> qh/kh/vh, Q pre-scaled)
//           -> trv (vh -> vt [b,h,d,n])
//           -> flash attention (K/V LDS-staged dbuf + XOR swizzle, swapped QK^T)
//           -> GEMM2 (same template, f32 out + bias)
// GEMM: 128x128 tile, BK=32, 256 thr / 4 waves, single-buffer 16KB LDS,
// {stage; sync; ds_read frags; 16 MFMA/wave; sync} x 24. Latency hidden by
// 4 co-resident blocks/CU (launch_bounds(256,4), m114 implicit overlap).
// LDS swizzle: chunk ^ ((row>>1)&3) -> 2-way (free) on 64B rows.
// ws usage: 80,216,064 bytes.

typedef unsigned short u16;
typedef unsigned int u32;
typedef __attribute__((ext_vector_type(8))) short short8;  // 8 x bf16 (4 VGPR)
typedef __attribute__((ext_vector_type(4))) float f32x4;

#define DEV static __device__ __forceinline__

DEV u16 f2bf(float f) {  // round-to-nearest-even f32 -> bf16 bits
  union { float f; u32 u; } v; v.f = f;
  return (u16)((v.u + 0x7FFFu + ((v.u >> 16) & 1u)) >> 16);
}

DEV void gload_lds16(const void* g, void* l) {
  // LDS dest is wave-uniform base; HW writes lane i at base + i*16B.
  __builtin_amdgcn_global_load_lds(
      (const __attribute__((address_space(1))) void*)g,
      (__attribute__((address_space(3))) void*)l, 16, 0, 0);
}

// ---------------- f32 -> bf16 elementwise (8 elems/thread) ----------------
__global__ void cvt_bf16_kernel(const float* __restrict__ in, u16* __restrict__ out, int n8) {
  int idx = blockIdx.x * blockDim.x + threadIdx.x;
  int stride = gridDim.x * blockDim.x;
  for (int i = idx; i < n8; i += stride) {
    float4 a = reinterpret_cast<const float4*>(in)[2 * i];
    float4 b = reinterpret_cast<const float4*>(in)[2 * i + 1];
    uint4 o;
    o.x = f2bf(a.x) | ((u32)f2bf(a.y) << 16);
    o.y = f2bf(a.z) | ((u32)f2bf(a.w) << 16);
    o.z = f2bf(b.x) | ((u32)f2bf(b.y) << 16);
    o.w = f2bf(b.z) | ((u32)f2bf(b.w) << 16);
    reinterpret_cast<uint4*>(out)[i] = o;
  }
}

// ------------- W [K][Nn] f32 -> Wt [Nn][K] bf16, 64x64 LDS tiles -------------
__global__ void trcvt_kernel(const float* __restrict__ in, u16* __restrict__ out,
                             int K, int Nn) {
  __shared__ u16 tile[64][72];
  int ntiles = Nn >> 6;
  int tk = blockIdx.x / ntiles, tn = blockIdx.x % ntiles;
  int k0 = tk << 6, n0 = tn << 6;
  int t = threadIdx.x;
  int r = t >> 4;            // 0..15
  int c4 = (t & 15) << 2;    // 0,4,..,60
#pragma unroll
  for (int ps = 0; ps < 4; ++ps) {
    int k = r + ps * 16;
    float4 v = *reinterpret_cast<const float4*>(&in[(size_t)(k0 + k) * Nn + n0 + c4]);
    tile[c4 + 0][k] = f2bf(v.x);
    tile[c4 + 1][k] = f2bf(v.y);
    tile[c4 + 2][k] = f2bf(v.z);
    tile[c4 + 3][k] = f2bf(v.w);
  }
  __syncthreads();
  int nr = t >> 3;           // 0..31
  int c8 = (t & 7) << 3;     // 0..56
#pragma unroll
  for (int ps = 0; ps < 2; ++ps) {
    int n = nr + ps * 32;
    uint4 v = *reinterpret_cast<const uint4*>(&tile[n][c8]);
    *reinterpret_cast<uint4*>(&out[(size_t)(n0 + n) * K + k0 + c8]) = v;
  }
}

// ------- vh [bh][n][64] -> vt [bh][64][n] (64-n tiles per (b,h)) -------
__global__ void trv_kernel(const u16* __restrict__ vh, u16* __restrict__ vt) {
  __shared__ u16 tile[64][72];
  int nt = blockIdx.x & 15;    // n tile 0..15
  int bh = blockIdx.x >> 4;    // 0..95
  int n0 = nt << 6;
  int t = threadIdx.x;
  int nr = t >> 3;             // 0..31
  int d8 = (t & 7) << 3;
  const u16* src = vh + ((size_t)bh * 1024 + n0) * 64;
#pragma unroll
  for (int ps = 0; ps < 2; ++ps) {
    int n = nr + ps * 32;
    uint4 v = *reinterpret_cast<const uint4*>(&src[(size_t)n * 64 + d8]);
    const u16* e = reinterpret_cast<const u16*>(&v);
#pragma unroll
    for (int j = 0; j < 8; ++j) tile[d8 + j][n] = e[j];
  }
  __syncthreads();
  u16* dst = vt + ((size_t)bh * 64) * 1024 + n0;
#pragma unroll
  for (int ps = 0; ps < 2; ++ps) {
    int d = nr + ps * 32;
    uint4 v = *reinterpret_cast<const uint4*>(&tile[d][d8]);
    *reinterpret_cast<uint4*>(&dst[(size_t)d * 1024 + d8]) = v;
  }
}

// ---------------- m97-structure bf16 GEMM, K fixed = 768 ----------------
// C[M][Nn] = A[M][768] * Bt[Nn][768]^T (+bias)
// MODE 0: f32 flat out.  MODE 2: split epilogue to qh/kh/vh [b,h,n,d], Q scaled.
template <int MODE>
__global__ __launch_bounds__(256, 4) void gemm_bt(
    const u16* __restrict__ A, const u16* __restrict__ Bt,
    const float* __restrict__ bias, void* __restrict__ Cout,
    u16* __restrict__ qh, u16* __restrict__ kh, u16* __restrict__ vh,
    int Nn) {
  __shared__ u16 As[128 * 32];   // 8 KB
  __shared__ u16 Bs[128 * 32];   // 8 KB
  const int nTn = Nn >> 7;
  const int nwg = gridDim.x;
  int wg = blockIdx.x;
  wg = (wg & 7) * (nwg >> 3) + (wg >> 3);   // XCD swizzle (nwg % 8 == 0)
  const int tm = wg / nTn, tn = wg % nTn;
  const int m0 = tm << 7, n0 = tn << 7;
  const int tid = threadIdx.x;
  const int w = tid >> 6, lane = tid & 63;
  const int g = lane >> 4, p = lane & 15;
  const int wr = w >> 1, wc = w & 1;        // wave -> 64x64 out at (wr*64, wc*64)

  // staging: one gload = 16 rows x 32 elems; lane = srow*4 + sc.
  // LDS(row, c) holds global chunk c ^ ((row>>1)&3) -> pre-swizzled source.
  const int srow = lane >> 2;               // 0..15
  const int schunk = (lane & 3) ^ ((srow >> 1) & 3);
  const u16* Asrc = A + (size_t)(m0 + srow) * 768 + schunk * 8;
  const u16* Bsrc = Bt + (size_t)(n0 + srow) * 768 + schunk * 8;
  // frag read: global chunk g of row (..16-aligned..)+p is at LDS chunk g^((p>>1)&3)
  const int csw = (g ^ ((p >> 1) & 3)) << 3;  // u16 offset within row

  f32x4 acc[4][4] = {};

  for (int kt = 0; kt < 768; kt += 32) {
#pragma unroll
    for (int i = 0; i < 2; ++i) {
      int trow = w * 32 + i * 16;  // tile rows this instr covers
      gload_lds16(Asrc + (size_t)trow * 768 + kt, &As[trow * 32]);
      gload_lds16(Bsrc + (size_t)trow * 768 + kt, &Bs[trow * 32]);
    }
    __syncthreads();
    short8 af[4], bf[4];
#pragma unroll
    for (int mb = 0; mb < 4; ++mb)
      af[mb] = *reinterpret_cast<const short8*>(&As[(wr * 64 + mb * 16 + p) * 32 + csw]);
#pragma unroll
    for (int nb = 0; nb < 4; ++nb)
      bf[nb] = *reinterpret_cast<const short8*>(&Bs[(wc * 64 + nb * 16 + p) * 32 + csw]);
#pragma unroll
    for (int mb = 0; mb < 4; ++mb)
#pragma unroll
      for (int nb = 0; nb < 4; ++nb)
        acc[mb][nb] = __builtin_amdgcn_mfma_f32_16x16x32_bf16(af[mb], bf[nb], acc[mb][nb], 0, 0, 0);
    __syncthreads();
  }

  const float qscale = 0.036084391824351615f;  // 1/sqrt(768)
#pragma unroll
  for (int nb = 0; nb < 4; ++nb) {
    int ncol = n0 + wc * 64 + nb * 16 + p;
    float bv = bias[ncol];
    if (MODE == 0) {
#pragma unroll
      for (int mb = 0; mb < 4; ++mb)
#pragma unroll
        for (int r = 0; r < 4; ++r) {
          int m = m0 + wr * 64 + mb * 16 + g * 4 + r;  // C/D: row=(lane>>4)*4+reg
          ((float*)Cout)[(size_t)m * Nn + ncol] = acc[mb][nb][r] + bv;
        }
    } else {
      int h64 = ncol >> 6;                 // 0..35
      int which = h64 / 12;                // 0=q 1=k 2=v
      int hh = h64 - which * 12;
      int d = ncol & 63;
      u16* dst = which == 0 ? qh : (which == 1 ? kh : vh);
      float sc = which == 0 ? qscale : 1.f;
#pragma unroll
      for (int mb = 0; mb < 4; ++mb)
#pragma unroll
        for (int r = 0; r < 4; ++r) {
          int m = m0 + wr * 64 + mb * 16 + g * 4 + r;
          int bb = m >> 10, nr = m & 1023;
          dst[(((size_t)bb * 12 + hh) * 1024 + nr) * 64 + d] = f2bf((acc[mb][nb][r] + bv) * sc);
        }
    }
  }
}

// ---------------- flash attention (unchanged from R2) ----------------
// grid: bh(96) * 8 q-tiles of 128 rows; 512 thr / 8 waves, wave owns 16 q-rows.
__global__ __launch_bounds__(512, 6) void attn_kernel(
    const u16* __restrict__ qh, const u16* __restrict__ kh,
    const u16* __restrict__ vt, u16* __restrict__ ao) {
  __shared__ u16 Ks[2][64 * 64];
  __shared__ u16 Vs[2][64 * 64];
  __shared__ u16 Ps[8][16 * 64];
  const int bid = blockIdx.x;
  const int qt = bid & 7;
  const int bh = bid >> 3;
  const int b = bh / 12, h = bh % 12;
  const int tid = threadIdx.x;
  const int w = tid >> 6, lane = tid & 63;
  const int g = lane >> 4, p = lane & 15;
  const int qrow = qt * 128 + w * 16;

  const u16* qbase = qh + ((size_t)bh * 1024 + qrow + p) * 64;
  short8 qf0 = *reinterpret_cast<const short8*>(qbase + g * 8);
  short8 qf1 = *reinterpret_cast<const short8*>(qbase + 32 + g * 8);

  const int ci = w * 64 + lane;              // 0..511
  const int crow = ci >> 3;                  // 0..63
  const int csw = (ci & 7) ^ (crow & 7);     // swizzled source chunk
  const u16* ksrc = kh + (((size_t)bh * 1024 + crow) << 6) + csw * 8;
  const u16* vsrc = vt + ((size_t)bh * 64 + crow) * 1024 + csw * 8;
  u16* myp = Ps[w];

  const int sw = p & 7;
  const int c0 = (g ^ sw) << 3;
  const int c1 = ((4 + g) ^ sw) << 3;

  float m_run = -1e30f, l_run = 0.f;
  f32x4 oacc[4] = {};

  gload_lds16(ksrc, &Ks[0][w * 512]);
  gload_lds16(vsrc, &Vs[0][w * 512]);
  __syncthreads();

  int buf = 0;
  for (int kt = 0; kt < 1024; kt += 64) {
    if (kt < 960) {
      gload_lds16(ksrc + ((kt + 64) << 6), &Ks[buf ^ 1][w * 512]);
      gload_lds16(vsrc + (kt + 64), &Vs[buf ^ 1][w * 512]);
    }

    f32x4 s[4];
    __builtin_amdgcn_s_setprio(1);
#pragma unroll
    for (int jb = 0; jb < 4; ++jb) {
      const u16* kb = &Ks[buf][(jb * 16 + p) * 64];
      short8 k0 = *reinterpret_cast<const short8*>(kb + c0);
      short8 k1 = *reinterpret_cast<const short8*>(kb + c1);
      f32x4 z = {};
      z = __builtin_amdgcn_mfma_f32_16x16x32_bf16(k0, qf0, z, 0, 0, 0);
      z = __builtin_amdgcn_mfma_f32_16x16x32_bf16(k1, qf1, z, 0, 0, 0);
      s[jb] = z;
    }
    __builtin_amdgcn_s_setprio(0);

    float tmax = -1e30f;
#pragma unroll
    for (int jb = 0; jb < 4; ++jb)
#pragma unroll
      for (int r = 0; r < 4; ++r) tmax = fmaxf(tmax, s[jb][r]);
    tmax = fmaxf(tmax, __shfl_xor(tmax, 16));
    tmax = fmaxf(tmax, __shfl_xor(tmax, 32));
    float m_new = fmaxf(m_run, tmax);
    float alpha = __expf(m_run - m_new);
    float lsum = 0.f;
#pragma unroll
    for (int jb = 0; jb < 4; ++jb)
#pragma unroll
      for (int r = 0; r < 4; ++r) {
        float e = __expf(s[jb][r] - m_new);
        s[jb][r] = e;
        lsum += e;
      }
    lsum += __shfl_xor(lsum, 16);
    lsum += __shfl_xor(lsum, 32);
    l_run = l_run * alpha + lsum;
    m_run = m_new;

#pragma unroll
    for (int jb = 0; jb < 4; ++jb) {
      uint2 pk;
      pk.x = f2bf(s[jb][0]) | ((u32)f2bf(s[jb][1]) << 16);
      pk.y = f2bf(s[jb][2]) | ((u32)f2bf(s[jb][3]) << 16);
      int c = 2 * jb + (g >> 1);
      *reinterpret_cast<uint2*>(&myp[p * 64 + ((c ^ sw) << 3) + ((g & 1) << 2)]) = pk;
    }

    float al[4];
#pragma unroll
    for (int r = 0; r < 4; ++r) al[r] = __shfl(alpha, g * 4 + r);
#pragma unroll
    for (int nb = 0; nb < 4; ++nb)
#pragma unroll
      for (int r = 0; r < 4; ++r) oacc[nb][r] *= al[r];

    short8 pa0 = *reinterpret_cast<const short8*>(&myp[p * 64 + c0]);
    short8 pa1 = *reinterpret_cast<const short8*>(&myp[p * 64 + c1]);
    __builtin_amdgcn_s_setprio(1);
#pragma unroll
    for (int nb = 0; nb < 4; ++nb) {
      const u16* vb = &Vs[buf][(nb * 16 + p) * 64];
      short8 v0 = *reinterpret_cast<const short8*>(vb + c0);
      short8 v1 = *reinterpret_cast<const short8*>(vb + c1);
      oacc[nb] = __builtin_amdgcn_mfma_f32_16x16x32_bf16(pa0, v0, oacc[nb], 0, 0, 0);
      oacc[nb] = __builtin_amdgcn_mfma_f32_16x16x32_bf16(pa1, v1, oacc[nb], 0, 0, 0);
    }
    __builtin_amdgcn_s_setprio(0);

    __syncthreads();
    buf ^= 1;
  }

  float li[4];
#pragma unroll
  for (int r = 0; r < 4; ++r) li[r] = 1.f / __shfl(l_run, g * 4 + r);
  u16* obase = ao + ((size_t)(b * 1024 + qrow)) * 768 + h * 64;
#pragma unroll
  for (int nb = 0; nb < 4; ++nb)
#pragma unroll
    for (int r = 0; r < 4; ++r)
      obase[(size_t)(g * 4 + r) * 768 + nb * 16 + p] = f2bf(oacc[nb][r] * li[r]);
}

// ---------------- launch ----------------
extern "C" void kernel_launch(void* const* d_in, const int* in_sizes, int n_in,
                              void* d_out, int out_size, void* d_ws, size_t ws_size,
                              hipStream_t stream) {
  const float* x = (const float*)d_in[0];      // [8,1024,768]
  const float* Wqkv = (const float*)d_in[1];   // [768,2304]
  const float* bqkv = (const float*)d_in[2];   // [2304]
  const float* Wfc = (const float*)d_in[3];    // [768,768]
  const float* bfc = (const float*)d_in[4];    // [768]
  float* out = (float*)d_out;                  // [8,1024,768] f32

  char* ws = (char*)d_ws;
  u16* xb    = (u16*)(ws);                 // 12,582,912 B : x bf16 [8192][768]
  u16* wqkvT = (u16*)(ws + 12582912);      //  3,538,944 B : [2304][768]
  u16* wfcT  = (u16*)(ws + 16121856);      //  1,179,648 B : [768][768]
  u16* qh    = (u16*)(ws + 17301504);      // 12,582,912 B : [96][1024][64] (scaled)
  u16* kh    = (u16*)(ws + 29884416);      // 12,582,912 B : [96][1024][64]
  u16* vh    = (u16*)(ws + 42467328);      // 12,582,912 B : [96][1024][64]
  u16* vt    = (u16*)(ws + 55050240);      // 12,582,912 B : [96][64][1024]
  u16* ao    = (u16*)(ws + 67633152);      // 12,582,912 B : [8192][768]

  cvt_bf16_kernel<<<2048, 256, 0, stream>>>(x, xb, (8192 * 768) / 8);
  trcvt_kernel<<<12 * 36, 256, 0, stream>>>(Wqkv, wqkvT, 768, 2304);
  trcvt_kernel<<<12 * 12, 256, 0, stream>>>(Wfc, wfcT, 768, 768);
  gemm_bt<2><<<64 * 18, 256, 0, stream>>>(xb, wqkvT, bqkv, nullptr, qh, kh, vh, 2304);
  trv_kernel<<<96 * 16, 256, 0, stream>>>(vh, vt);
  attn_kernel<<<96 * 8, 512, 0, stream>>>(qh, kh, vt, ao);
  gemm_bt<0><<<64 * 6, 256, 0, stream>>>(ao, wfcT, bfc, out, nullptr, nullptr, nullptr, 768);
}

// Round 6
// 140.103 us; speedup vs baseline: 1.0116x; 1.0116x over previous
//
#include <hip/hip_runtime.h>

// MultiHeadSelfAttention: B=8 N=1024 E=768 H=12 D=64
// Pipeline: cvt(x) / transpose-cvt(Wqkv,Wfc)
//           -> GEMM1 (dbuf bf16 mfma, epilogue -> qh/kh/vh, Q pre-scaled)
//           -> trv (vh -> vt [b,h,d,n])
//           -> flash attention (K/V LDS-staged dbuf + XOR swizzle, swapped QK^T)
//           -> GEMM2 (same template, f32 out + bias)
// GEMM: 128x128 tile, BK=32, 256 thr / 4 waves, DOUBLE-buffered 32KB LDS,
// ONE __syncthreads per K-iter: {8 ds_read(k); 4 gload_lds(k+1, other buf);
// 16 MFMA; barrier}. The barrier's vmcnt(0) drain lands after ~700cy of
// compute, so next-tile load latency is hidden inside the block (no reliance
// on cross-block coverage, which counters show never materialized).
// LDS swizzle: chunk ^ ((row>>1)&3) -> 2-way (free) on 64B rows (R5: 0 conflicts).
// ws usage: 80,216,064 bytes.

typedef unsigned short u16;
typedef unsigned int u32;
typedef __attribute__((ext_vector_type(8))) short short8;  // 8 x bf16 (4 VGPR)
typedef __attribute__((ext_vector_type(4))) float f32x4;

#define DEV static __device__ __forceinline__

DEV u16 f2bf(float f) {  // round-to-nearest-even f32 -> bf16 bits
  union { float f; u32 u; } v; v.f = f;
  return (u16)((v.u + 0x7FFFu + ((v.u >> 16) & 1u)) >> 16);
}

DEV void gload_lds16(const void* g, void* l) {
  // LDS dest is wave-uniform base; HW writes lane i at base + i*16B.
  __builtin_amdgcn_global_load_lds(
      (const __attribute__((address_space(1))) void*)g,
      (__attribute__((address_space(3))) void*)l, 16, 0, 0);
}

// ---------------- f32 -> bf16 elementwise (8 elems/thread) ----------------
__global__ void cvt_bf16_kernel(const float* __restrict__ in, u16* __restrict__ out, int n8) {
  int idx = blockIdx.x * blockDim.x + threadIdx.x;
  int stride = gridDim.x * blockDim.x;
  for (int i = idx; i < n8; i += stride) {
    float4 a = reinterpret_cast<const float4*>(in)[2 * i];
    float4 b = reinterpret_cast<const float4*>(in)[2 * i + 1];
    uint4 o;
    o.x = f2bf(a.x) | ((u32)f2bf(a.y) << 16);
    o.y = f2bf(a.z) | ((u32)f2bf(a.w) << 16);
    o.z = f2bf(b.x) | ((u32)f2bf(b.y) << 16);
    o.w = f2bf(b.z) | ((u32)f2bf(b.w) << 16);
    reinterpret_cast<uint4*>(out)[i] = o;
  }
}

// ------------- W [K][Nn] f32 -> Wt [Nn][K] bf16, 64x64 LDS tiles -------------
__global__ void trcvt_kernel(const float* __restrict__ in, u16* __restrict__ out,
                             int K, int Nn) {
  __shared__ u16 tile[64][72];
  int ntiles = Nn >> 6;
  int tk = blockIdx.x / ntiles, tn = blockIdx.x % ntiles;
  int k0 = tk << 6, n0 = tn << 6;
  int t = threadIdx.x;
  int r = t >> 4;            // 0..15
  int c4 = (t & 15) << 2;    // 0,4,..,60
#pragma unroll
  for (int ps = 0; ps < 4; ++ps) {
    int k = r + ps * 16;
    float4 v = *reinterpret_cast<const float4*>(&in[(size_t)(k0 + k) * Nn + n0 + c4]);
    tile[c4 + 0][k] = f2bf(v.x);
    tile[c4 + 1][k] = f2bf(v.y);
    tile[c4 + 2][k] = f2bf(v.z);
    tile[c4 + 3][k] = f2bf(v.w);
  }
  __syncthreads();
  int nr = t >> 3;           // 0..31
  int c8 = (t & 7) << 3;     // 0..56
#pragma unroll
  for (int ps = 0; ps < 2; ++ps) {
    int n = nr + ps * 32;
    uint4 v = *reinterpret_cast<const uint4*>(&tile[n][c8]);
    *reinterpret_cast<uint4*>(&out[(size_t)(n0 + n) * K + k0 + c8]) = v;
  }
}

// ------- vh [bh][n][64] -> vt [bh][64][n] (64-n tiles per (b,h)) -------
__global__ void trv_kernel(const u16* __restrict__ vh, u16* __restrict__ vt) {
  __shared__ u16 tile[64][72];
  int nt = blockIdx.x & 15;    // n tile 0..15
  int bh = blockIdx.x >> 4;    // 0..95
  int n0 = nt << 6;
  int t = threadIdx.x;
  int nr = t >> 3;             // 0..31
  int d8 = (t & 7) << 3;
  const u16* src = vh + ((size_t)bh * 1024 + n0) * 64;
#pragma unroll
  for (int ps = 0; ps < 2; ++ps) {
    int n = nr + ps * 32;
    uint4 v = *reinterpret_cast<const uint4*>(&src[(size_t)n * 64 + d8]);
    const u16* e = reinterpret_cast<const u16*>(&v);
#pragma unroll
    for (int j = 0; j < 8; ++j) tile[d8 + j][n] = e[j];
  }
  __syncthreads();
  u16* dst = vt + ((size_t)bh * 64) * 1024 + n0;
#pragma unroll
  for (int ps = 0; ps < 2; ++ps) {
    int d = nr + ps * 32;
    uint4 v = *reinterpret_cast<const uint4*>(&tile[d][d8]);
    *reinterpret_cast<uint4*>(&dst[(size_t)d * 1024 + d8]) = v;
  }
}

// ---------------- dbuf bf16 GEMM, K fixed = 768 ----------------
// C[M][Nn] = A[M][768] * Bt[Nn][768]^T (+bias)
// MODE 0: f32 flat out.  MODE 2: split epilogue to qh/kh/vh [b,h,n,d], Q scaled.
template <int MODE>
__global__ __launch_bounds__(256, 4) void gemm_bt(
    const u16* __restrict__ A, const u16* __restrict__ Bt,
    const float* __restrict__ bias, void* __restrict__ Cout,
    u16* __restrict__ qh, u16* __restrict__ kh, u16* __restrict__ vh,
    int Nn) {
  __shared__ u16 As[2][128 * 32];   // 16 KB
  __shared__ u16 Bs[2][128 * 32];   // 16 KB
  const int nTn = Nn >> 7;
  const int nwg = gridDim.x;
  int wg = blockIdx.x;
  wg = (wg & 7) * (nwg >> 3) + (wg >> 3);   // XCD swizzle (nwg % 8 == 0)
  const int tm = wg / nTn, tn = wg % nTn;
  const int m0 = tm << 7, n0 = tn << 7;
  const int tid = threadIdx.x;
  const int w = tid >> 6, lane = tid & 63;
  const int g = lane >> 4, p = lane & 15;
  const int wr = w >> 1, wc = w & 1;        // wave -> 64x64 out at (wr*64, wc*64)

  // staging: one gload = 16 rows x 32 elems; lane = srow*4 + sc.
  // LDS(row, c) holds global chunk c ^ ((row>>1)&3) -> pre-swizzled source.
  const int srow = lane >> 2;               // 0..15
  const int schunk = (lane & 3) ^ ((srow >> 1) & 3);
  const u16* Asrc = A + (size_t)(m0 + srow) * 768 + schunk * 8;
  const u16* Bsrc = Bt + (size_t)(n0 + srow) * 768 + schunk * 8;
  // frag read: global chunk g of row (16-aligned)+p is at LDS chunk g^((p>>1)&3)
  const int csw = (g ^ ((p >> 1) & 3)) << 3;  // u16 offset within row

  f32x4 acc[4][4] = {};

#define STAGE(kt, sbuf)                                                         \
  do {                                                                          \
    _Pragma("unroll")                                                           \
    for (int i = 0; i < 2; ++i) {                                               \
      int trow = w * 32 + i * 16;                                               \
      gload_lds16(Asrc + (size_t)trow * 768 + (kt) * 32, &As[sbuf][trow * 32]); \
      gload_lds16(Bsrc + (size_t)trow * 768 + (kt) * 32, &Bs[sbuf][trow * 32]); \
    }                                                                           \
  } while (0)

  // prologue: stage tile 0 (syncthreads drains vmcnt -> tile 0 ready)
  STAGE(0, 0);
  __syncthreads();

  int buf = 0;
  for (int k = 0; k < 24; ++k) {
    const u16* as = As[buf];
    const u16* bs = Bs[buf];
    // 8 ds_read_b128: this tile's fragments
    short8 af[4], bf[4];
#pragma unroll
    for (int mb = 0; mb < 4; ++mb)
      af[mb] = *reinterpret_cast<const short8*>(&as[(wr * 64 + mb * 16 + p) * 32 + csw]);
#pragma unroll
    for (int nb = 0; nb < 4; ++nb)
      bf[nb] = *reinterpret_cast<const short8*>(&bs[(wc * 64 + nb * 16 + p) * 32 + csw]);
    // issue next tile into the other buffer (flies during MFMA below;
    // safe: all reads of buf^1's old tile finished at previous barrier)
    if (k < 23) STAGE(k + 1, buf ^ 1);
#pragma unroll
    for (int mb = 0; mb < 4; ++mb)
#pragma unroll
      for (int nb = 0; nb < 4; ++nb)
        acc[mb][nb] = __builtin_amdgcn_mfma_f32_16x16x32_bf16(af[mb], bf[nb], acc[mb][nb], 0, 0, 0);
    // single barrier: drains stage(k+1) (latency overlapped by the work
    // above) and closes all reads of tile k before it gets overwritten.
    __syncthreads();
    buf ^= 1;
  }
#undef STAGE

  const float qscale = 0.036084391824351615f;  // 1/sqrt(768)
#pragma unroll
  for (int nb = 0; nb < 4; ++nb) {
    int ncol = n0 + wc * 64 + nb * 16 + p;
    float bv = bias[ncol];
    if (MODE == 0) {
#pragma unroll
      for (int mb = 0; mb < 4; ++mb)
#pragma unroll
        for (int r = 0; r < 4; ++r) {
          int m = m0 + wr * 64 + mb * 16 + g * 4 + r;  // C/D: row=(lane>>4)*4+reg
          ((float*)Cout)[(size_t)m * Nn + ncol] = acc[mb][nb][r] + bv;
        }
    } else {
      int h64 = ncol >> 6;                 // 0..35
      int which = h64 / 12;                // 0=q 1=k 2=v
      int hh = h64 - which * 12;
      int d = ncol & 63;
      u16* dst = which == 0 ? qh : (which == 1 ? kh : vh);
      float sc = which == 0 ? qscale : 1.f;
#pragma unroll
      for (int mb = 0; mb < 4; ++mb)
#pragma unroll
        for (int r = 0; r < 4; ++r) {
          int m = m0 + wr * 64 + mb * 16 + g * 4 + r;
          int bb = m >> 10, nr = m & 1023;
          dst[(((size_t)bb * 12 + hh) * 1024 + nr) * 64 + d] = f2bf((acc[mb][nb][r] + bv) * sc);
        }
    }
  }
}

// ---------------- flash attention (unchanged from R2) ----------------
// grid: bh(96) * 8 q-tiles of 128 rows; 512 thr / 8 waves, wave owns 16 q-rows.
__global__ __launch_bounds__(512, 6) void attn_kernel(
    const u16* __restrict__ qh, const u16* __restrict__ kh,
    const u16* __restrict__ vt, u16* __restrict__ ao) {
  __shared__ u16 Ks[2][64 * 64];
  __shared__ u16 Vs[2][64 * 64];
  __shared__ u16 Ps[8][16 * 64];
  const int bid = blockIdx.x;
  const int qt = bid & 7;
  const int bh = bid >> 3;
  const int b = bh / 12, h = bh % 12;
  const int tid = threadIdx.x;
  const int w = tid >> 6, lane = tid & 63;
  const int g = lane >> 4, p = lane & 15;
  const int qrow = qt * 128 + w * 16;

  const u16* qbase = qh + ((size_t)bh * 1024 + qrow + p) * 64;
  short8 qf0 = *reinterpret_cast<const short8*>(qbase + g * 8);
  short8 qf1 = *reinterpret_cast<const short8*>(qbase + 32 + g * 8);

  const int ci = w * 64 + lane;              // 0..511
  const int crow = ci >> 3;                  // 0..63
  const int csw = (ci & 7) ^ (crow & 7);     // swizzled source chunk
  const u16* ksrc = kh + (((size_t)bh * 1024 + crow) << 6) + csw * 8;
  const u16* vsrc = vt + ((size_t)bh * 64 + crow) * 1024 + csw * 8;
  u16* myp = Ps[w];

  const int sw = p & 7;
  const int c0 = (g ^ sw) << 3;
  const int c1 = ((4 + g) ^ sw) << 3;

  float m_run = -1e30f, l_run = 0.f;
  f32x4 oacc[4] = {};

  gload_lds16(ksrc, &Ks[0][w * 512]);
  gload_lds16(vsrc, &Vs[0][w * 512]);
  __syncthreads();

  int buf = 0;
  for (int kt = 0; kt < 1024; kt += 64) {
    if (kt < 960) {
      gload_lds16(ksrc + ((kt + 64) << 6), &Ks[buf ^ 1][w * 512]);
      gload_lds16(vsrc + (kt + 64), &Vs[buf ^ 1][w * 512]);
    }

    f32x4 s[4];
    __builtin_amdgcn_s_setprio(1);
#pragma unroll
    for (int jb = 0; jb < 4; ++jb) {
      const u16* kb = &Ks[buf][(jb * 16 + p) * 64];
      short8 k0 = *reinterpret_cast<const short8*>(kb + c0);
      short8 k1 = *reinterpret_cast<const short8*>(kb + c1);
      f32x4 z = {};
      z = __builtin_amdgcn_mfma_f32_16x16x32_bf16(k0, qf0, z, 0, 0, 0);
      z = __builtin_amdgcn_mfma_f32_16x16x32_bf16(k1, qf1, z, 0, 0, 0);
      s[jb] = z;
    }
    __builtin_amdgcn_s_setprio(0);

    float tmax = -1e30f;
#pragma unroll
    for (int jb = 0; jb < 4; ++jb)
#pragma unroll
      for (int r = 0; r < 4; ++r) tmax = fmaxf(tmax, s[jb][r]);
    tmax = fmaxf(tmax, __shfl_xor(tmax, 16));
    tmax = fmaxf(tmax, __shfl_xor(tmax, 32));
    float m_new = fmaxf(m_run, tmax);
    float alpha = __expf(m_run - m_new);
    float lsum = 0.f;
#pragma unroll
    for (int jb = 0; jb < 4; ++jb)
#pragma unroll
      for (int r = 0; r < 4; ++r) {
        float e = __expf(s[jb][r] - m_new);
        s[jb][r] = e;
        lsum += e;
      }
    lsum += __shfl_xor(lsum, 16);
    lsum += __shfl_xor(lsum, 32);
    l_run = l_run * alpha + lsum;
    m_run = m_new;

#pragma unroll
    for (int jb = 0; jb < 4; ++jb) {
      uint2 pk;
      pk.x = f2bf(s[jb][0]) | ((u32)f2bf(s[jb][1]) << 16);
      pk.y = f2bf(s[jb][2]) | ((u32)f2bf(s[jb][3]) << 16);
      int c = 2 * jb + (g >> 1);
      *reinterpret_cast<uint2*>(&myp[p * 64 + ((c ^ sw) << 3) + ((g & 1) << 2)]) = pk;
    }

    float al[4];
#pragma unroll
    for (int r = 0; r < 4; ++r) al[r] = __shfl(alpha, g * 4 + r);
#pragma unroll
    for (int nb = 0; nb < 4; ++nb)
#pragma unroll
      for (int r = 0; r < 4; ++r) oacc[nb][r] *= al[r];

    short8 pa0 = *reinterpret_cast<const short8*>(&myp[p * 64 + c0]);
    short8 pa1 = *reinterpret_cast<const short8*>(&myp[p * 64 + c1]);
    __builtin_amdgcn_s_setprio(1);
#pragma unroll
    for (int nb = 0; nb < 4; ++nb) {
      const u16* vb = &Vs[buf][(nb * 16 + p) * 64];
      short8 v0 = *reinterpret_cast<const short8*>(vb + c0);
      short8 v1 = *reinterpret_cast<const short8*>(vb + c1);
      oacc[nb] = __builtin_amdgcn_mfma_f32_16x16x32_bf16(pa0, v0, oacc[nb], 0, 0, 0);
      oacc[nb] = __builtin_amdgcn_mfma_f32_16x16x32_bf16(pa1, v1, oacc[nb], 0, 0, 0);
    }
    __builtin_amdgcn_s_setprio(0);

    __syncthreads();
    buf ^= 1;
  }

  float li[4];
#pragma unroll
  for (int r = 0; r < 4; ++r) li[r] = 1.f / __shfl(l_run, g * 4 + r);
  u16* obase = ao + ((size_t)(b * 1024 + qrow)) * 768 + h * 64;
#pragma unroll
  for (int nb = 0; nb < 4; ++nb)
#pragma unroll
    for (int r = 0; r < 4; ++r)
      obase[(size_t)(g * 4 + r) * 768 + nb * 16 + p] = f2bf(oacc[nb][r] * li[r]);
}

// ---------------- launch ----------------
extern "C" void kernel_launch(void* const* d_in, const int* in_sizes, int n_in,
                              void* d_out, int out_size, void* d_ws, size_t ws_size,
                              hipStream_t stream) {
  const float* x = (const float*)d_in[0];      // [8,1024,768]
  const float* Wqkv = (const float*)d_in[1];   // [768,2304]
  const float* bqkv = (const float*)d_in[2];   // [2304]
  const float* Wfc = (const float*)d_in[3];    // [768,768]
  const float* bfc = (const float*)d_in[4];    // [768]
  float* out = (float*)d_out;                  // [8,1024,768] f32

  char* ws = (char*)d_ws;
  u16* xb    = (u16*)(ws);                 // 12,582,912 B : x bf16 [8192][768]
  u16* wqkvT = (u16*)(ws + 12582912);      //  3,538,944 B : [2304][768]
  u16* wfcT  = (u16*)(ws + 16121856);      //  1,179,648 B : [768][768]
  u16* qh    = (u16*)(ws + 17301504);      // 12,582,912 B : [96][1024][64] (scaled)
  u16* kh    = (u16*)(ws + 29884416);      // 12,582,912 B : [96][1024][64]
  u16* vh    = (u16*)(ws + 42467328);      // 12,582,912 B : [96][1024][64]
  u16* vt    = (u16*)(ws + 55050240);      // 12,582,912 B : [96][64][1024]
  u16* ao    = (u16*)(ws + 67633152);      // 12,582,912 B : [8192][768]

  cvt_bf16_kernel<<<2048, 256, 0, stream>>>(x, xb, (8192 * 768) / 8);
  trcvt_kernel<<<12 * 36, 256, 0, stream>>>(Wqkv, wqkvT, 768, 2304);
  trcvt_kernel<<<12 * 12, 256, 0, stream>>>(Wfc, wfcT, 768, 768);
  gemm_bt<2><<<64 * 18, 256, 0, stream>>>(xb, wqkvT, bqkv, nullptr, qh, kh, vh, 2304);
  trv_kernel<<<96 * 16, 256, 0, stream>>>(vh, vt);
  attn_kernel<<<96 * 8, 512, 0, stream>>>(qh, kh, vt, ao);
  gemm_bt<0><<<64 * 6, 256, 0, stream>>>(ao, wfcT, bfc, out, nullptr, nullptr, nullptr, 768);
}